// Round 15
// baseline (84.039 us; speedup 1.0000x reference)
//
#include <hip/hip_runtime.h>

#define B_ 2048
#define T_ 500
#define BT (B_ * T_)

// ---------------------------------------------------------------------------
// Masked Izhikevich Euler step — association order matches the reference
// exactly (DT=0.25, all a=0.02 -> DT*a = 0.005f). Invalid lanes hold state.
// ---------------------------------------------------------------------------
__device__ __forceinline__ float izh_m(float& v, float& u, float I,
                                       float b, float c, float d, bool valid) {
    float t  = 0.04f * v * v + 5.0f * v + 140.0f - u + I;
    float v_ = v + 0.25f * t;
    float u_ = u + 0.005f * (b * v - u);
    float z  = (v_ >= 30.0f) ? 1.0f : 0.0f;
    float vn = (v_ >= 30.0f) ? c : v_;
    float un = u_ + z * d;
    if (!valid) { z = 0.f; vn = v; un = u; }
    v = vn; u = un;
    return z;
}

// DPP row-shift-right by 1 within each 16-lane row; OOB lanes read 0.
__device__ __forceinline__ float dpp_shr1(float x) {
    return __int_as_float(__builtin_amdgcn_update_dpp(
        0, __float_as_int(x), 0x111, 0xf, 0xf, true));
}

// v_readlane broadcast (SALU path, no DS).
__device__ __forceinline__ float rlane(float x, int l) {
    return __int_as_float(__builtin_amdgcn_readlane(__float_as_int(x), l));
}

// ---------------------------------------------------------------------------
// v7 MONOLITHIC kernel: 2048 blocks x 64 threads, ONE wave per block doing
// load + reduce + scan + dump for ONE batch row (both channels). 8 waves/CU
// (2 per SIMD) of homogeneous work -> per-wave stalls hidden by the SIMD
// mate. Zero barriers. Scan: gap-3 systolic, all-distance-1 slot layout
// (0:L 1:E 2:I 3:idle 4:L' 5:E' 6:T 7:M per 8-lane half; L',E' duplicated),
// active in lane-group 0 only. Input tile sums produced by the reference's
// exact xor-tree and consumed via v_readlane.
// ---------------------------------------------------------------------------
__global__ __launch_bounds__(64, 2) void mono_scan_kernel(
        const float* __restrict__ in, const float* __restrict__ w24,
        float* __restrict__ out) {
    __shared__ float ring[32 * 14];    // [32 slots][14 floats] (one chain-row)

    const int lane  = threadIdx.x;
    const int b     = blockIdx.x;      // one batch row per block
    const int grp   = lane >> 4;       // 0 = scan-active group
    const int slot  = lane & 15;
    const int chl   = slot >> 3;       // 0 = channel 1, 1 = channel 2
    const int role8 = slot & 7;        // 0:L 1:E 2:I 3:idle 4:L' 5:E' 6:T 7:M

    const float a0   = chl ? w24[12] : w24[0];
    const float W1v  = chl ? w24[13] : w24[1];
    const float W4v  = chl ? w24[16] : w24[4];
    const float W5x  = chl ? w24[17] : w24[5];
    const float W6v  = chl ? w24[18] : w24[6];
    const float W8v  = chl ? w24[20] : w24[8];
    const float W11v = chl ? w24[23] : w24[11];
    const float W2 = w24[2], W3 = w24[3], W9 = w24[9], W10 = w24[10];

    float pb, pcc, pd, v, u, wA, wB, wC, wD;
    float fL = 0.f, fE = 0.f, fITM = 0.f;
    int offs;
    if (grp != 0) {                        // inactive groups: bounded idle
        pb=0.25f; pcc=-65.f; pd=6.f;   v=-64.f; u=-16.f;
        wA=0.f; wB=0.f;  wC=0.f; wD=0.f; offs=9;
    } else if (role8 == 0 || role8 == 4) { // L / L': w2*(zp*w1) + w3*z2(self)
        pb=0.20f; pcc=-65.f; pd=6.f;   v=-70.f; u=-14.f;
        wA=W2;  wB=W1v;  wC=0.f; wD=W3;  offs=0; fL=1.f;
    } else if (role8 == 1 || role8 == 5) { // E / E': zp*w4 + z2*w5 (z2 <- slot-1)
        pb=0.25f; pcc=-55.f; pd=0.05f; v=-64.f; u=-16.f;
        wA=1.f; wB=W4v;  wC=W5x; wD=0.f; offs=3; fE=1.f;
    } else if (role8 == 2) {               // I: z3*w6 (z3 <- slot-1 = E)
        pb=0.25f; pcc=-65.f; pd=6.f;   v=-64.f; u=-16.f;
        wA=1.f; wB=W6v;  wC=0.f; wD=0.f; offs=6; fITM=1.f;
    } else if (role8 == 6) {               // T: w9*(z3*w8)+w10*z5(self) (z3 <- slot-1 = E')
        pb=0.20f; pcc=-50.f; pd=2.f;   v=-70.f; u=-14.f;
        wA=W9;  wB=W8v;  wC=0.f; wD=W10; offs=6; fITM=1.f;
    } else if (role8 == 7) {               // M: z5*w11 (z5 <- slot-1 = T)
        pb=0.25f; pcc=-65.f; pd=6.f;   v=-64.f; u=-16.f;
        wA=1.f; wB=W11v; wC=0.f; wD=0.f; offs=9; fITM=1.f;
    } else {                               // slot 3: idle
        pb=0.25f; pcc=-65.f; pd=6.f;   v=-64.f; u=-16.f;
        wA=0.f; wB=0.f;  wC=0.f; wD=0.f; offs=9;
    }
    // ring pairs (ch1): p0=(z2,vL)@s0 p1=(z3,vE)@s1 p2=(z4,vI)@s2
    //                   p3=(z5,vT)@s6 p4=(z6,vM)@s7 ; ch2: p5=(z62,vM2)@s15
    const bool wr = (grp == 0) &&
        ((chl == 0 && (role8 <= 2 || role8 == 6 || role8 == 7)) ||
         (chl == 1 && role8 == 7));
    int p = 0;
    if (role8 == 1) p = 1;
    else if (role8 == 2) p = 2;
    else if (role8 == 6) p = 3;
    else if (role8 == 7) p = chl ? 5 : 4;
    const int ringoff = 2 * p;

    float z_last = 0.f, in_p1 = 0.f, in_p2 = 0.f;
    float zp1 = 0.f, zp2 = 0.f, zp3 = 0.f;

    const float* inb = in + (size_t)b * T_ * 64;
    float4 L0[4], L1[4];                       // load ping-pong (static idx)
    float sE0, sE1, sE2, sE3, sO0, sO1, sO2, sO3;  // S-sum ping-pong

// 4 contiguous 1KB wave-loads: instr q covers t = t0+4q+grp, chunk = slot.
#define ISSUE(M, BUF) {                                                        \
    const int t0i = 16 * (M);                                                  \
    _Pragma("unroll")                                                          \
    for (int q = 0; q < 4; ++q) {                                              \
        const int tq = (t0i + 4 * q + 3 <= 499) ? 4 * q : 0;                   \
        BUF[q] = *(const float4*)(inb + (size_t)(t0i + tq + grp) * 64          \
                                      + slot * 4);                             \
    }                                                                          \
}

// Reference rowsum tree, bit-exact: leaf (x+y)+(z+w), xor1,2,4,8 (16-lane).
// Butterfly leaves the identical sum in every lane of the group.
#define REDUCE(BUF, S0, S1, S2, S3) {                                          \
    float s_; float4 vv_;                                                      \
    vv_ = BUF[0]; s_ = (vv_.x + vv_.y) + (vv_.z + vv_.w);                      \
    s_ += __shfl_xor(s_, 1); s_ += __shfl_xor(s_, 2);                          \
    s_ += __shfl_xor(s_, 4); s_ += __shfl_xor(s_, 8); S0 = s_;                 \
    vv_ = BUF[1]; s_ = (vv_.x + vv_.y) + (vv_.z + vv_.w);                      \
    s_ += __shfl_xor(s_, 1); s_ += __shfl_xor(s_, 2);                          \
    s_ += __shfl_xor(s_, 4); s_ += __shfl_xor(s_, 8); S1 = s_;                 \
    vv_ = BUF[2]; s_ = (vv_.x + vv_.y) + (vv_.z + vv_.w);                      \
    s_ += __shfl_xor(s_, 1); s_ += __shfl_xor(s_, 2);                          \
    s_ += __shfl_xor(s_, 4); s_ += __shfl_xor(s_, 8); S2 = s_;                 \
    vv_ = BUF[3]; s_ = (vv_.x + vv_.y) + (vv_.z + vv_.w);                      \
    s_ += __shfl_xor(s_, 1); s_ += __shfl_xor(s_, 2);                          \
    s_ += __shfl_xor(s_, 4); s_ += __shfl_xor(s_, 8); S3 = s_;                 \
}

#define SYS_ITER(SV, VEXPR, I_) {                                              \
    float in0 = in_p2;                                                         \
    in_p2 = in_p1;                                                             \
    in_p1 = dpp_shr1(z_last);                                                  \
    float zpc = (SV) * a0;                                                     \
    float X = (fL * zpc + fE * zp3) + fITM * in0;                              \
    float Isyn = wA * (X * wB) + wC * in0 + wD * z_last;                       \
    float znew = izh_m(v, u, Isyn, pb, pcc, pd, (VEXPR));                      \
    if (wr) *(float2*)(ringp + (I_) * 14) = make_float2(znew, v);              \
    zp3 = zp2; zp2 = zp1; zp1 = zpc;                                           \
    z_last = znew;                                                             \
}

// Full 16-iter group: iter I uses S_{I>>2} broadcast from lane (I&3)*16.
#define G16(S0, S1, S2, S3, VF)                                                \
    SYS_ITER(rlane(S0,  0), VF(0),  0)  SYS_ITER(rlane(S0, 16), VF(1),  1)     \
    SYS_ITER(rlane(S0, 32), VF(2),  2)  SYS_ITER(rlane(S0, 48), VF(3),  3)     \
    SYS_ITER(rlane(S1,  0), VF(4),  4)  SYS_ITER(rlane(S1, 16), VF(5),  5)     \
    SYS_ITER(rlane(S1, 32), VF(6),  6)  SYS_ITER(rlane(S1, 48), VF(7),  7)     \
    SYS_ITER(rlane(S2,  0), VF(8),  8)  SYS_ITER(rlane(S2, 16), VF(9),  9)     \
    SYS_ITER(rlane(S2, 32), VF(10), 10) SYS_ITER(rlane(S2, 48), VF(11), 11)    \
    SYS_ITER(rlane(S3,  0), VF(12), 12) SYS_ITER(rlane(S3, 16), VF(13), 13)    \
    SYS_ITER(rlane(S3, 32), VF(14), 14) SYS_ITER(rlane(S3, 48), VF(15), 15)

// Epilogue group (period 31): t=496..499 real, rest SV=0 with ramp-down.
#define G16_EPI(S0)                                                            \
    SYS_ITER(rlane(S0,  0), VF_EPI(0),  0)  SYS_ITER(rlane(S0, 16), VF_EPI(1),  1) \
    SYS_ITER(rlane(S0, 32), VF_EPI(2),  2)  SYS_ITER(rlane(S0, 48), VF_EPI(3),  3) \
    SYS_ITER(0.f, VF_EPI(4),  4)  SYS_ITER(0.f, VF_EPI(5),  5)                 \
    SYS_ITER(0.f, VF_EPI(6),  6)  SYS_ITER(0.f, VF_EPI(7),  7)                 \
    SYS_ITER(0.f, VF_EPI(8),  8)  SYS_ITER(0.f, VF_EPI(9),  9)                 \
    SYS_ITER(0.f, VF_EPI(10), 10) SYS_ITER(0.f, VF_EPI(11), 11)                \
    SYS_ITER(0.f, VF_EPI(12), 12) SYS_ITER(0.f, VF_EPI(13), 13)                \
    SYS_ITER(0.f, VF_EPI(14), 14) SYS_ITER(0.f, VF_EPI(15), 15)

#define VF_PRO(i)  ((i) >= offs)
#define VF_ONE(i)  true
#define VF_EPI(i)  ((i) <= 3 + offs)

// DUMP(K): t in [16K-9, 16K+6]; reads z2@t, z3@t+3, z4/z5@t+6, z6/z62@t+9.
// Same-wave LDS RAW -> compiler-ordered via lgkmcnt; no barrier needed.
#define DUMP(K) {                                                              \
    const int t = 16 * (K) - 9 + slot;                                         \
    if (grp == 0 && 0 <= t && t <= 499) {                                      \
        float2 a2 = *(const float2*)&ring[((t)     & 31) * 14 + 0];            \
        float2 b2 = *(const float2*)&ring[((t + 3) & 31) * 14 + 2];            \
        float2 c1 = *(const float2*)&ring[((t + 6) & 31) * 14 + 4];            \
        float2 c2 = *(const float2*)&ring[((t + 6) & 31) * 14 + 6];            \
        float2 e1 = *(const float2*)&ring[((t + 9) & 31) * 14 + 8];            \
        float2 e2 = *(const float2*)&ring[((t + 9) & 31) * 14 + 10];           \
        const size_t g = (size_t)b * T_ + t;                                   \
        out[g]          = e1.x;   /* o_spikes  = z6  */                        \
        out[BT + g]     = e1.y;   /* v         = vM  */                        \
        out[2 * BT + g] = e2.x;   /* o_spikes2 = z62 */                        \
        out[3 * BT + g] = e2.y;   /* v2        = vM2 */                        \
        ((float4*)out)[BT + g]     = make_float4(a2.x, b2.x, c1.x, c2.x);      \
        ((float4*)out)[2 * BT + g] = make_float4(a2.y, b2.y, c1.y, c2.y);      \
    }                                                                          \
}

    // ---------------- prologue ----------------
    ISSUE(0, L0)
    REDUCE(L0, sE0, sE1, sE2, sE3)   // one-time wait on first 4 loads
    ISSUE(1, L1)

    // ---------------- main: periods 0..31, unrolled x2 for ping-pong --------
    for (int k = 0; k < 32; k += 2) {
        // even period k: scan sqE; reduce L1 -> sqO; issue k+2 -> L0
        if (k + 2 < 32) { ISSUE(k + 2, L0) }
        if (k + 1 < 32) { REDUCE(L1, sO0, sO1, sO2, sO3) }
        {
            float* ringp = ring + ringoff;            // (k even) slots 0..15
            if (k == 0) { G16(sE0, sE1, sE2, sE3, VF_PRO) }
            else        { G16(sE0, sE1, sE2, sE3, VF_ONE) }
        }
        DUMP(k)
        // odd period k+1: scan sqO; reduce L0 -> sqE; issue k+3 -> L1
        if (k + 3 < 32) { ISSUE(k + 3, L1) }
        if (k + 2 < 32) { REDUCE(L0, sE0, sE1, sE2, sE3) }
        {
            float* ringp = ring + 16 * 14 + ringoff;  // (k odd) slots 16..31
            if (k + 1 == 31) { G16_EPI(sO0) }
            else             { G16(sO0, sO1, sO2, sO3, VF_ONE) }
        }
        DUMP(k + 1)
    }

#undef ISSUE
#undef REDUCE
#undef SYS_ITER
#undef G16
#undef G16_EPI
#undef VF_PRO
#undef VF_ONE
#undef VF_EPI
#undef DUMP
}

extern "C" void kernel_launch(void* const* d_in, const int* in_sizes, int n_in,
                              void* d_out, int out_size, void* d_ws, size_t ws_size,
                              hipStream_t stream) {
    const float* in = (const float*)d_in[0];
    const float* w  = (const float*)d_in[1];
    float* out = (float*)d_out;

    // 2048 single-wave blocks (one batch row each); 8 waves/CU, no barriers.
    mono_scan_kernel<<<B_, 64, 0, stream>>>(in, w, out);
}

// Round 16
// 76.213 us; speedup vs baseline: 1.1027x; 1.1027x over previous
//
#include <hip/hip_runtime.h>

#define B_ 2048
#define T_ 500
#define BT (B_ * T_)

// ---------------------------------------------------------------------------
// Masked Izhikevich Euler step — association order matches the reference
// exactly (DT=0.25, all a=0.02 -> DT*a = 0.005f). Invalid lanes hold state.
// ---------------------------------------------------------------------------
__device__ __forceinline__ float izh_m(float& v, float& u, float I,
                                       float b, float c, float d, bool valid) {
    float t  = 0.04f * v * v + 5.0f * v + 140.0f - u + I;
    float v_ = v + 0.25f * t;
    float u_ = u + 0.005f * (b * v - u);
    float z  = (v_ >= 30.0f) ? 1.0f : 0.0f;
    float vn = (v_ >= 30.0f) ? c : v_;
    float un = u_ + z * d;
    if (!valid) { z = 0.f; vn = v; un = u; }
    v = vn; u = un;
    return z;
}

// DPP row-shift-right by 1 within each 16-lane row; OOB lanes read 0.
__device__ __forceinline__ float dpp_shr1(float x) {
    return __int_as_float(__builtin_amdgcn_update_dpp(
        0, __float_as_int(x), 0x111, 0xf, 0xf, true));
}

// LDS-only workgroup barrier (lgkmcnt, never vmcnt) — prefetch loads stay in
// flight across it; global stores drain at kernel end.
#define BAR() do {                                                             \
    asm volatile("s_waitcnt lgkmcnt(0)" ::: "memory");                         \
    __builtin_amdgcn_s_barrier();                                              \
    __builtin_amdgcn_sched_barrier(0);                                         \
} while (0)

// ---------------------------------------------------------------------------
// FUSED producer-consumer kernel, v9: ONE barrier per 32 steps (17 total vs
// 33 in v6) — attacks the producer<->consumer convoy overhead, the only
// never-isolated lever (both waves' work fits in <1/2 the measured period).
//   wave 0 = scanner: two 16-iter groups per super-period (gap-3 systolic,
//            all-distance-1 layout, unchanged).
//   wave 1 = loader: REDUCE(k+2)->S_lds[(k+2)&3], ISSUE(k+4) refill,
//            REDUCE(k+3), ISSUE(k+5), then DUMP(k-2), DUMP(k-1).
// S_lds 4-deep (scanner reads {k,k+1}&3, loader writes {k+2,k+3}&3 —
// disjoint). Ring 128 slots: write window {k,k+1}, read {k-3..k-1} — 5 of 8
// periods, race-free. Loads sit >=1 super-period in flight before use.
// ---------------------------------------------------------------------------
__global__ __launch_bounds__(128) void fused_scan9_kernel(
        const float* __restrict__ in, const float* __restrict__ w24,
        float* __restrict__ out) {
    __shared__ float S_lds[256];       // [4 bufs][4 rows][16 t]
    __shared__ float ring[128 * 56];   // [128 slots][4 chains * 14 floats]

    const int tid   = threadIdx.x;
    const int wid   = tid >> 6;        // 0 = scanner, 1 = loader
    const int lane  = tid & 63;
    const int bbase = blockIdx.x << 2; // 4 batch rows per block

    // ---------------- scanner per-lane config ----------------
    const int c     = lane >> 4;       // chain 0..3
    const int slot  = lane & 15;
    const int chl   = slot >> 3;       // 0 = channel 1, 1 = channel 2
    const int role8 = slot & 7;        // 0:L 1:E 2:I 3:idle 4:L' 5:E' 6:T 7:M

    const float a0   = chl ? w24[12] : w24[0];
    const float W1v  = chl ? w24[13] : w24[1];
    const float W4v  = chl ? w24[16] : w24[4];
    const float W5x  = chl ? w24[17] : w24[5];
    const float W6v  = chl ? w24[18] : w24[6];
    const float W8v  = chl ? w24[20] : w24[8];
    const float W11v = chl ? w24[23] : w24[11];
    const float W2 = w24[2], W3 = w24[3], W9 = w24[9], W10 = w24[10];

    float pb, pcc, pd, v, u, wA, wB, wC, wD;
    float fL = 0.f, fE = 0.f, fITM = 0.f;
    int offs;
    if (role8 == 0 || role8 == 4) {        // L / L': w2*(zp*w1) + w3*z2(self)
        pb=0.20f; pcc=-65.f; pd=6.f;   v=-70.f; u=-14.f;
        wA=W2;  wB=W1v;  wC=0.f; wD=W3;  offs=0; fL=1.f;
    } else if (role8 == 1 || role8 == 5) { // E / E': zp*w4 + z2*w5 (z2 <- slot-1)
        pb=0.25f; pcc=-55.f; pd=0.05f; v=-64.f; u=-16.f;
        wA=1.f; wB=W4v;  wC=W5x; wD=0.f; offs=3; fE=1.f;
    } else if (role8 == 2) {               // I: z3*w6 (z3 <- slot-1 = E)
        pb=0.25f; pcc=-65.f; pd=6.f;   v=-64.f; u=-16.f;
        wA=1.f; wB=W6v;  wC=0.f; wD=0.f; offs=6; fITM=1.f;
    } else if (role8 == 6) {               // T: w9*(z3*w8)+w10*z5(self) (z3 <- slot-1 = E')
        pb=0.20f; pcc=-50.f; pd=2.f;   v=-70.f; u=-14.f;
        wA=W9;  wB=W8v;  wC=0.f; wD=W10; offs=6; fITM=1.f;
    } else if (role8 == 7) {               // M: z5*w11 (z5 <- slot-1 = T)
        pb=0.25f; pcc=-65.f; pd=6.f;   v=-64.f; u=-16.f;
        wA=1.f; wB=W11v; wC=0.f; wD=0.f; offs=9; fITM=1.f;
    } else {                               // slot 3: idle
        pb=0.25f; pcc=-65.f; pd=6.f;   v=-64.f; u=-16.f;
        wA=0.f; wB=0.f;  wC=0.f; wD=0.f; offs=9;
    }
    // ring pairs (ch1): p0=(z2,vL)@s0 p1=(z3,vE)@s1 p2=(z4,vI)@s2
    //                   p3=(z5,vT)@s6 p4=(z6,vM)@s7 ; ch2: p5=(z62,vM2)@s15
    const bool wr = (chl == 0 && (role8 <= 2 || role8 == 6 || role8 == 7))
                 || (chl == 1 && role8 == 7);
    int p = 0;
    if (role8 == 1) p = 1;
    else if (role8 == 2) p = 2;
    else if (role8 == 6) p = 3;
    else if (role8 == 7) p = chl ? 5 : 4;
    const int ringoff = c * 14 + 2 * p;

    float z_last = 0.f, in_p1 = 0.f, in_p2 = 0.f;
    float zp1 = 0.f, zp2 = 0.f, zp3 = 0.f;

    const float* inb = in + (size_t)bbase * T_ * 64;
    // loader ping-pong register buffers (static indexing via full unroll)
    float4 Ae[8], Ao[8], Be[8], Bo[8];

#define ISSUE(KK, BE, BO) {                                                    \
    const int t0i = 16 * (KK);                                                 \
    _Pragma("unroll")                                                          \
    for (int pp = 0; pp < 8; ++pp) {                                           \
        const int rt = pp * 8 + (lane >> 3);                                   \
        const int row = rt >> 4, tt = rt & 15;                                 \
        const int tcl = (t0i + tt <= 499) ? tt : 0;                            \
        const float* ap = inb + ((size_t)row * T_ + t0i + tcl) * 64            \
                              + (lane & 7) * 8;                                \
        BE[pp] = *(const float4*)ap;                                           \
        BO[pp] = *(const float4*)(ap + 4);                                     \
    }                                                                          \
}

#define REDUCE(KK, BE, BO) {                                                   \
    float* sw = S_lds + ((KK) & 3) * 64;                                       \
    const int t0r = 16 * (KK);                                                 \
    _Pragma("unroll")                                                          \
    for (int pp = 0; pp < 8; ++pp) {                                           \
        float4 e = BE[pp], o = BO[pp];                                         \
        float s = ((e.x + e.y) + (e.z + e.w)) + ((o.x + o.y) + (o.z + o.w));   \
        s += __shfl_xor(s, 1);                                                 \
        s += __shfl_xor(s, 2);                                                 \
        s += __shfl_xor(s, 4);                                                 \
        const int rt = pp * 8 + (lane >> 3);                                   \
        const int row = rt >> 4, tt = rt & 15;                                 \
        if ((lane & 7) == 0) sw[row * 16 + tt] = (t0r + tt <= 499) ? s : 0.f;  \
    }                                                                          \
}

#define SYS_ITER(SV, VEXPR, I_) {                                              \
    float in0 = in_p2;                                                         \
    in_p2 = in_p1;                                                             \
    in_p1 = dpp_shr1(z_last);                                                  \
    float zpc = (SV) * a0;                                                     \
    float X = (fL * zpc + fE * zp3) + fITM * in0;                              \
    float Isyn = wA * (X * wB) + wC * in0 + wD * z_last;                       \
    float znew = izh_m(v, u, Isyn, pb, pcc, pd, (VEXPR));                      \
    if (wr) *(float2*)(ringp + (I_) * 56) = make_float2(znew, v);              \
    zp3 = zp2; zp2 = zp1; zp1 = zpc;                                           \
    z_last = znew;                                                             \
}

#define GROUP16(VF)                                                            \
    SYS_ITER(g0.x, VF(0),  0)  SYS_ITER(g0.y, VF(1),  1)                       \
    SYS_ITER(g0.z, VF(2),  2)  SYS_ITER(g0.w, VF(3),  3)                       \
    SYS_ITER(g1.x, VF(4),  4)  SYS_ITER(g1.y, VF(5),  5)                       \
    SYS_ITER(g1.z, VF(6),  6)  SYS_ITER(g1.w, VF(7),  7)                       \
    SYS_ITER(g2.x, VF(8),  8)  SYS_ITER(g2.y, VF(9),  9)                       \
    SYS_ITER(g2.z, VF(10), 10) SYS_ITER(g2.w, VF(11), 11)                      \
    SYS_ITER(g3.x, VF(12), 12) SYS_ITER(g3.y, VF(13), 13)                      \
    SYS_ITER(g3.z, VF(14), 14) SYS_ITER(g3.w, VF(15), 15)

#define VF_PRO(i)  ((i) >= offs)
#define VF_ONE(i)  true
#define VF_EPI(i)  ((i) <= 3 + offs)

// DUMP(K): on the loader, >=1 super-period after period K completed.
// Ring 128-deep; concurrent scanner writes are 2-3 periods ahead of the
// read window (5 consecutive periods of 8 in the ring) -> no aliasing.
#define DUMP(K) {                                                              \
    const int td = lane & 15;                                                  \
    const int cc = lane >> 4;                                                  \
    const int t  = 16 * (K) - 9 + td;                                          \
    if (0 <= t && t <= 499) {                                                  \
        const float* rb = ring + cc * 14;                                      \
        float2 a2 = *(const float2*)&rb[((t)      & 127) * 56 + 0];            \
        float2 b2 = *(const float2*)&rb[((t + 3)  & 127) * 56 + 2];            \
        float2 c1 = *(const float2*)&rb[((t + 6)  & 127) * 56 + 4];            \
        float2 c2 = *(const float2*)&rb[((t + 6)  & 127) * 56 + 6];            \
        float2 e1 = *(const float2*)&rb[((t + 9)  & 127) * 56 + 8];            \
        float2 e2 = *(const float2*)&rb[((t + 9)  & 127) * 56 + 10];           \
        const size_t g = (size_t)(bbase + cc) * T_ + t;                        \
        out[g]          = e1.x;   /* o_spikes  = z6  */                        \
        out[BT + g]     = e1.y;   /* v         = vM  */                        \
        out[2 * BT + g] = e2.x;   /* o_spikes2 = z62 */                        \
        out[3 * BT + g] = e2.y;   /* v2        = vM2 */                        \
        ((float4*)out)[BT + g]     = make_float4(a2.x, b2.x, c1.x, c2.x);      \
        ((float4*)out)[2 * BT + g] = make_float4(a2.y, b2.y, c1.y, c2.y);      \
    }                                                                          \
}

// Scanner period K: slots (K&7)*16 .. +15 of the 128-deep ring.
#define SCANP(K, VFSEL) {                                                      \
    const float4* sp = (const float4*)(S_lds + ((K) & 3) * 64 + c * 16);       \
    float4 g0 = sp[0], g1 = sp[1], g2 = sp[2], g3 = sp[3];                     \
    float* ringp = ring + ((K) & 7) * 896 + ringoff;                           \
    __builtin_amdgcn_s_setprio(1);                                             \
    GROUP16(VFSEL)                                                             \
    __builtin_amdgcn_s_setprio(0);                                             \
}

    // ---------------- prologue: S for periods 0,1; loads for 2,3 in flight --
    if (wid == 1) {
        ISSUE(0, Ae, Ao)
        REDUCE(0, Ae, Ao)      // one-time vmcnt wait
        ISSUE(1, Be, Bo)
        REDUCE(1, Be, Bo)
        ISSUE(2, Ae, Ao)
        ISSUE(3, Be, Bo)
    }
    BAR();

    // ---------------- main: 16 super-periods, ONE barrier each -------------
    for (int k = 0; k < 32; k += 2) {
        if (wid == 0) {
            if (k == 0) { SCANP(0, VF_PRO) } else { SCANP(k, VF_ONE) }
            if (k + 1 == 31) { SCANP(31, VF_EPI) } else { SCANP(k + 1, VF_ONE) }
        } else {
            if (k + 2 < 32) { REDUCE(k + 2, Ae, Ao) }
            if (k + 4 < 32) { ISSUE(k + 4, Ae, Ao) }
            if (k + 3 < 32) { REDUCE(k + 3, Be, Bo) }
            if (k + 5 < 32) { ISSUE(k + 5, Be, Bo) }
            if (k >= 2) { DUMP(k - 2) }
            if (k >= 2) { DUMP(k - 1) }
        }
        BAR();
    }
    // final dumps: periods 30, 31 (scanner finished them before the last BAR)
    if (wid == 1) { DUMP(30) DUMP(31) }

#undef ISSUE
#undef REDUCE
#undef SYS_ITER
#undef GROUP16
#undef VF_PRO
#undef VF_ONE
#undef VF_EPI
#undef DUMP
#undef SCANP
}

extern "C" void kernel_launch(void* const* d_in, const int* in_sizes, int n_in,
                              void* d_out, int out_size, void* d_ws, size_t ws_size,
                              hipStream_t stream) {
    const float* in = (const float*)d_in[0];
    const float* w  = (const float*)d_in[1];
    float* out = (float*)d_out;

    // 512 blocks x 128 threads (1 scanner wave + 1 loader wave),
    // 4 batch rows per block; no workspace needed.
    fused_scan9_kernel<<<512, 128, 0, stream>>>(in, w, out);
}

// Round 17
// 74.592 us; speedup vs baseline: 1.1266x; 1.0217x over previous
//
#include <hip/hip_runtime.h>

#define B_ 2048
#define T_ 500
#define BT (B_ * T_)

// ---------------------------------------------------------------------------
// Masked Izhikevich Euler step — association order matches the reference
// exactly (DT=0.25, all a=0.02 -> DT*a = 0.005f). Invalid lanes hold state.
// ---------------------------------------------------------------------------
__device__ __forceinline__ float izh_m(float& v, float& u, float I,
                                       float b, float c, float d, bool valid) {
    float t  = 0.04f * v * v + 5.0f * v + 140.0f - u + I;
    float v_ = v + 0.25f * t;
    float u_ = u + 0.005f * (b * v - u);
    float z  = (v_ >= 30.0f) ? 1.0f : 0.0f;
    float vn = (v_ >= 30.0f) ? c : v_;
    float un = u_ + z * d;
    if (!valid) { z = 0.f; vn = v; un = u; }
    v = vn; u = un;
    return z;
}

// DPP row-shift-right by 1 within each 16-lane row; OOB lanes read 0.
__device__ __forceinline__ float dpp_shr1(float x) {
    return __int_as_float(__builtin_amdgcn_update_dpp(
        0, __float_as_int(x), 0x111, 0xf, 0xf, true));
}

// LDS-only workgroup barrier (lgkmcnt, never vmcnt) — prefetch loads stay in
// flight across it; global stores drain at kernel end.
#define BAR() do {                                                             \
    asm volatile("s_waitcnt lgkmcnt(0)" ::: "memory");                         \
    __builtin_amdgcn_s_barrier();                                              \
    __builtin_amdgcn_sched_barrier(0);                                         \
} while (0)

// ---------------------------------------------------------------------------
// FUSED producer-consumer kernel, v10 = v6 + ZERO-CROSS-LANE loader.
//   wave 0 = scanner: gap-3 systolic, all-distance-1 layout (unchanged).
//   wave 1 = loader: lane (r=lane>>4, tt=lane&15) loads its own (row,t)
//            atom's 64 floats (16 x float4, per-lane contiguous) and reduces
//            IN-LANE with the exact pairwise tree (bit-identical association
//            to the validated xor-tree); one ds_write_b32 -> S_lds.
//            REDUCE: 24 ds_bpermute -> 0 DS ops. DUMP on loader (v6).
// ---------------------------------------------------------------------------
__global__ __launch_bounds__(128) void fused_scan10_kernel(
        const float* __restrict__ in, const float* __restrict__ w24,
        float* __restrict__ out) {
    __shared__ float S_lds[128];       // [2 bufs][4 rows][16 t]
    __shared__ float ring[64 * 56];    // [64 slots][4 chains * 14 floats]

    const int tid   = threadIdx.x;
    const int wid   = tid >> 6;        // 0 = scanner, 1 = loader
    const int lane  = tid & 63;
    const int bbase = blockIdx.x << 2; // 4 batch rows per block

    // ---------------- scanner per-lane config ----------------
    const int c     = lane >> 4;       // chain 0..3
    const int slot  = lane & 15;
    const int chl   = slot >> 3;       // 0 = channel 1, 1 = channel 2
    const int role8 = slot & 7;        // 0:L 1:E 2:I 3:idle 4:L' 5:E' 6:T 7:M

    const float a0   = chl ? w24[12] : w24[0];
    const float W1v  = chl ? w24[13] : w24[1];
    const float W4v  = chl ? w24[16] : w24[4];
    const float W5x  = chl ? w24[17] : w24[5];
    const float W6v  = chl ? w24[18] : w24[6];
    const float W8v  = chl ? w24[20] : w24[8];
    const float W11v = chl ? w24[23] : w24[11];
    const float W2 = w24[2], W3 = w24[3], W9 = w24[9], W10 = w24[10];

    float pb, pcc, pd, v, u, wA, wB, wC, wD;
    float fL = 0.f, fE = 0.f, fITM = 0.f;
    int offs;
    if (role8 == 0 || role8 == 4) {        // L / L': w2*(zp*w1) + w3*z2(self)
        pb=0.20f; pcc=-65.f; pd=6.f;   v=-70.f; u=-14.f;
        wA=W2;  wB=W1v;  wC=0.f; wD=W3;  offs=0; fL=1.f;
    } else if (role8 == 1 || role8 == 5) { // E / E': zp*w4 + z2*w5 (z2 <- slot-1)
        pb=0.25f; pcc=-55.f; pd=0.05f; v=-64.f; u=-16.f;
        wA=1.f; wB=W4v;  wC=W5x; wD=0.f; offs=3; fE=1.f;
    } else if (role8 == 2) {               // I: z3*w6 (z3 <- slot-1 = E)
        pb=0.25f; pcc=-65.f; pd=6.f;   v=-64.f; u=-16.f;
        wA=1.f; wB=W6v;  wC=0.f; wD=0.f; offs=6; fITM=1.f;
    } else if (role8 == 6) {               // T: w9*(z3*w8)+w10*z5(self) (z3 <- slot-1 = E')
        pb=0.20f; pcc=-50.f; pd=2.f;   v=-70.f; u=-14.f;
        wA=W9;  wB=W8v;  wC=0.f; wD=W10; offs=6; fITM=1.f;
    } else if (role8 == 7) {               // M: z5*w11 (z5 <- slot-1 = T)
        pb=0.25f; pcc=-65.f; pd=6.f;   v=-64.f; u=-16.f;
        wA=1.f; wB=W11v; wC=0.f; wD=0.f; offs=9; fITM=1.f;
    } else {                               // slot 3: idle
        pb=0.25f; pcc=-65.f; pd=6.f;   v=-64.f; u=-16.f;
        wA=0.f; wB=0.f;  wC=0.f; wD=0.f; offs=9;
    }
    // ring pairs (ch1): p0=(z2,vL)@s0 p1=(z3,vE)@s1 p2=(z4,vI)@s2
    //                   p3=(z5,vT)@s6 p4=(z6,vM)@s7 ; ch2: p5=(z62,vM2)@s15
    const bool wr = (chl == 0 && (role8 <= 2 || role8 == 6 || role8 == 7))
                 || (chl == 1 && role8 == 7);
    int p = 0;
    if (role8 == 1) p = 1;
    else if (role8 == 2) p = 2;
    else if (role8 == 6) p = 3;
    else if (role8 == 7) p = chl ? 5 : 4;
    const int ringoff = c * 14 + 2 * p;

    float z_last = 0.f, in_p1 = 0.f, in_p2 = 0.f;
    float zp1 = 0.f, zp2 = 0.f, zp3 = 0.f;

    // loader lane mapping: one (row, t) atom per lane.
    const int lr = lane >> 4, ltt = lane & 15;
    const float* inb = in + (size_t)bbase * T_ * 64;
    // loader ping-pong register buffers (static indexing via full unroll)
    float4 A[16], Bv[16];

// Lane loads its own atom: 16 x float4, contiguous 256B per lane.
// Tail: per-lane clamp to t=t0 (re-read), S-write below masks to 0.
#define ISSUE(KK, BUF) {                                                       \
    const int t0i = 16 * (KK);                                                 \
    const int ttc = (t0i + ltt <= 499) ? ltt : 0;                              \
    const float* ap = inb + ((size_t)lr * T_ + t0i + ttc) * 64;                \
    _Pragma("unroll")                                                          \
    for (int ck = 0; ck < 16; ++ck) BUF[ck] = *(const float4*)(ap + ck * 4);   \
}

// In-lane pairwise tree, association-identical to the validated xor-tree:
// q_c=(x+y)+(z+w); a_i=q2i+q2i+1; b_i=a2i+a2i+1; c_i=b2i+b2i+1; s=c0+c1.
// Zero cross-lane ops; one ds_write_b32 per lane.
#define REDUCE(KK, BUF) {                                                      \
    float* sw = S_lds + ((KK) & 1) * 64;                                       \
    float q0,q1,q2,q3,q4,q5,q6,q7,q8,q9,q10,q11,q12,q13,q14,q15;               \
    { float4 t_;                                                               \
      t_=BUF[0];  q0 =(t_.x+t_.y)+(t_.z+t_.w);                                 \
      t_=BUF[1];  q1 =(t_.x+t_.y)+(t_.z+t_.w);                                 \
      t_=BUF[2];  q2 =(t_.x+t_.y)+(t_.z+t_.w);                                 \
      t_=BUF[3];  q3 =(t_.x+t_.y)+(t_.z+t_.w);                                 \
      t_=BUF[4];  q4 =(t_.x+t_.y)+(t_.z+t_.w);                                 \
      t_=BUF[5];  q5 =(t_.x+t_.y)+(t_.z+t_.w);                                 \
      t_=BUF[6];  q6 =(t_.x+t_.y)+(t_.z+t_.w);                                 \
      t_=BUF[7];  q7 =(t_.x+t_.y)+(t_.z+t_.w);                                 \
      t_=BUF[8];  q8 =(t_.x+t_.y)+(t_.z+t_.w);                                 \
      t_=BUF[9];  q9 =(t_.x+t_.y)+(t_.z+t_.w);                                 \
      t_=BUF[10]; q10=(t_.x+t_.y)+(t_.z+t_.w);                                 \
      t_=BUF[11]; q11=(t_.x+t_.y)+(t_.z+t_.w);                                 \
      t_=BUF[12]; q12=(t_.x+t_.y)+(t_.z+t_.w);                                 \
      t_=BUF[13]; q13=(t_.x+t_.y)+(t_.z+t_.w);                                 \
      t_=BUF[14]; q14=(t_.x+t_.y)+(t_.z+t_.w);                                 \
      t_=BUF[15]; q15=(t_.x+t_.y)+(t_.z+t_.w); }                               \
    float a0_=q0+q1, a1_=q2+q3, a2_=q4+q5, a3_=q6+q7;                          \
    float a4_=q8+q9, a5_=q10+q11, a6_=q12+q13, a7_=q14+q15;                    \
    float b0_=a0_+a1_, b1_=a2_+a3_, b2_=a4_+a5_, b3_=a6_+a7_;                  \
    float c0_=b0_+b1_, c1_=b2_+b3_;                                            \
    float s_ = c0_ + c1_;                                                      \
    sw[lr * 16 + ltt] = (16 * (KK) + ltt <= 499) ? s_ : 0.f;                   \
}

#define SYS_ITER(SV, VEXPR, I_) {                                              \
    float in0 = in_p2;                                                         \
    in_p2 = in_p1;                                                             \
    in_p1 = dpp_shr1(z_last);                                                  \
    float zpc = (SV) * a0;                                                     \
    float X = (fL * zpc + fE * zp3) + fITM * in0;                              \
    float Isyn = wA * (X * wB) + wC * in0 + wD * z_last;                       \
    float znew = izh_m(v, u, Isyn, pb, pcc, pd, (VEXPR));                      \
    if (wr) *(float2*)(ringp + (I_) * 56) = make_float2(znew, v);              \
    zp3 = zp2; zp2 = zp1; zp1 = zpc;                                           \
    z_last = znew;                                                             \
}

#define GROUP16(VF)                                                            \
    SYS_ITER(g0.x, VF(0),  0)  SYS_ITER(g0.y, VF(1),  1)                       \
    SYS_ITER(g0.z, VF(2),  2)  SYS_ITER(g0.w, VF(3),  3)                       \
    SYS_ITER(g1.x, VF(4),  4)  SYS_ITER(g1.y, VF(5),  5)                       \
    SYS_ITER(g1.z, VF(6),  6)  SYS_ITER(g1.w, VF(7),  7)                       \
    SYS_ITER(g2.x, VF(8),  8)  SYS_ITER(g2.y, VF(9),  9)                       \
    SYS_ITER(g2.z, VF(10), 10) SYS_ITER(g2.w, VF(11), 11)                      \
    SYS_ITER(g3.x, VF(12), 12) SYS_ITER(g3.y, VF(13), 13)                      \
    SYS_ITER(g3.z, VF(14), 14) SYS_ITER(g3.w, VF(15), 15)

#define VF_PRO(i)  ((i) >= offs)
#define VF_ONE(i)  true
#define VF_EPI(i)  ((i) <= 3 + offs)

// DUMP(K): on the loader, one period after K completed. Ring 64-deep;
// concurrent scanner writes are 16..40 iters ahead of the read window.
#define DUMP(K) {                                                              \
    const int td = lane & 15;                                                  \
    const int cc = lane >> 4;                                                  \
    const int t  = 16 * (K) - 9 + td;                                          \
    if (0 <= t && t <= 499) {                                                  \
        const float* rb = ring + cc * 14;                                      \
        float2 a2 = *(const float2*)&rb[((t)     & 63) * 56 + 0];              \
        float2 b2 = *(const float2*)&rb[((t + 3) & 63) * 56 + 2];              \
        float2 c1 = *(const float2*)&rb[((t + 6) & 63) * 56 + 4];              \
        float2 c2 = *(const float2*)&rb[((t + 6) & 63) * 56 + 6];              \
        float2 e1 = *(const float2*)&rb[((t + 9) & 63) * 56 + 8];              \
        float2 e2 = *(const float2*)&rb[((t + 9) & 63) * 56 + 10];             \
        const size_t g = (size_t)(bbase + cc) * T_ + t;                        \
        out[g]          = e1.x;   /* o_spikes  = z6  */                        \
        out[BT + g]     = e1.y;   /* v         = vM  */                        \
        out[2 * BT + g] = e2.x;   /* o_spikes2 = z62 */                        \
        out[3 * BT + g] = e2.y;   /* v2        = vM2 */                        \
        ((float4*)out)[BT + g]     = make_float4(a2.x, b2.x, c1.x, c2.x);      \
        ((float4*)out)[2 * BT + g] = make_float4(a2.y, b2.y, c1.y, c2.y);      \
    }                                                                          \
}

// Scanner period K: slots (K&3)*16 .. +15 of the 64-deep ring.
#define SCANP(K, VFSEL) {                                                      \
    const float4* sp = (const float4*)(S_lds + ((K) & 1) * 64 + c * 16);       \
    float4 g0 = sp[0], g1 = sp[1], g2 = sp[2], g3 = sp[3];                     \
    float* ringp = ring + ((K) & 3) * 896 + ringoff;                           \
    __builtin_amdgcn_s_setprio(1);                                             \
    GROUP16(VFSEL)                                                             \
    __builtin_amdgcn_s_setprio(0);                                             \
}

    // ---------------- prologue ----------------
    if (wid == 1) {
        ISSUE(0, A)
        REDUCE(0, A)           // one-time vmcnt wait on first atom loads
        ISSUE(1, Bv)
    }
    BAR();                     // S_lds buf0 ready; ISSUE(1) stays in flight

    // ---------------- main: periods 0..31 (unrolled x2 for reg ping-pong) ---
    for (int k = 0; k < 32; k += 2) {
        if (wid == 0) {
            if (k == 0) { SCANP(k, VF_PRO) } else { SCANP(k, VF_ONE) }
        } else {
            if (k + 2 < 32) { ISSUE(k + 2, A) }
            if (k + 1 < 32) { REDUCE(k + 1, Bv) }
            if (k >= 1) { DUMP(k - 1) }
        }
        BAR();
        if (wid == 0) {
            if (k + 1 == 31) { SCANP(k + 1, VF_EPI) } else { SCANP(k + 1, VF_ONE) }
        } else {
            if (k + 3 < 32) { ISSUE(k + 3, Bv) }
            if (k + 2 < 32) { REDUCE(k + 2, A) }
            DUMP(k)
        }
        BAR();
    }
    // final dump (period 31's tail), after the last BAR
    if (wid == 1) { DUMP(31) }

#undef ISSUE
#undef REDUCE
#undef SYS_ITER
#undef GROUP16
#undef VF_PRO
#undef VF_ONE
#undef VF_EPI
#undef DUMP
#undef SCANP
}

extern "C" void kernel_launch(void* const* d_in, const int* in_sizes, int n_in,
                              void* d_out, int out_size, void* d_ws, size_t ws_size,
                              hipStream_t stream) {
    const float* in = (const float*)d_in[0];
    const float* w  = (const float*)d_in[1];
    float* out = (float*)d_out;

    // 512 blocks x 128 threads (1 scanner wave + 1 loader wave),
    // 4 batch rows per block; no workspace needed.
    fused_scan10_kernel<<<512, 128, 0, stream>>>(in, w, out);
}

// Round 18
// 70.071 us; speedup vs baseline: 1.1994x; 1.0645x over previous
//
#include <hip/hip_runtime.h>

#define B_ 2048
#define T_ 500
#define BT (B_ * T_)

// ---------------------------------------------------------------------------
// Masked Izhikevich Euler step — association order matches the reference
// exactly (DT=0.25, all a=0.02 -> DT*a = 0.005f). Invalid lanes hold state.
// ---------------------------------------------------------------------------
__device__ __forceinline__ float izh_m(float& v, float& u, float I,
                                       float b, float c, float d, bool valid) {
    float t  = 0.04f * v * v + 5.0f * v + 140.0f - u + I;
    float v_ = v + 0.25f * t;
    float u_ = u + 0.005f * (b * v - u);
    float z  = (v_ >= 30.0f) ? 1.0f : 0.0f;
    float vn = (v_ >= 30.0f) ? c : v_;
    float un = u_ + z * d;
    if (!valid) { z = 0.f; vn = v; un = u; }
    v = vn; u = un;
    return z;
}

// DPP row-shift-right by 1 within each 16-lane row; OOB lanes read 0.
__device__ __forceinline__ float dpp_shr1(float x) {
    return __int_as_float(__builtin_amdgcn_update_dpp(
        0, __float_as_int(x), 0x111, 0xf, 0xf, true));
}
// quad_perm [1,0,3,2] = lane^1 within quads
__device__ __forceinline__ float dpp_qx1(float x) {
    return __int_as_float(__builtin_amdgcn_update_dpp(
        0, __float_as_int(x), 0xB1, 0xf, 0xf, true));
}
// quad_perm [2,3,0,1] = lane^2 within quads
__device__ __forceinline__ float dpp_qx2(float x) {
    return __int_as_float(__builtin_amdgcn_update_dpp(
        0, __float_as_int(x), 0x4E, 0xf, 0xf, true));
}

// LDS-only workgroup barrier (lgkmcnt, never vmcnt).
#define BAR() do {                                                             \
    asm volatile("s_waitcnt lgkmcnt(0)" ::: "memory");                         \
    __builtin_amdgcn_s_barrier();                                              \
    __builtin_amdgcn_sched_barrier(0);                                         \
} while (0)

// ---------------------------------------------------------------------------
// v11: ONE ROW PER BLOCK, 2048 blocks x 128 threads (scanner + loader wave).
// 8 blocks/CU -> 16 waves/CU -> ~4 waves/SIMD (2 scanners + 2 loaders):
// a second scanner wave on each SIMD fills the first's dependency-chain
// bubbles (the measured ~7-10 cyc/instr solo-wave wall). Scanner code is
// identical to v6/v10; only chain 0 (lanes 0-15: ch1 slots 0-7, ch2 8-15)
// stores. Loader: 4 KB/period, in-lane + quad-DPP tree (bit-exact), 2-period
// register ping-pong, DUMP one period behind (64-deep ring, race-free).
// ---------------------------------------------------------------------------
__global__ __launch_bounds__(128, 4) void fused_scan11_kernel(
        const float* __restrict__ in, const float* __restrict__ w24,
        float* __restrict__ out) {
    __shared__ float S_lds[128];       // [2 bufs][64] (only [0..15] written)
    __shared__ float ring[64 * 14];    // [64 slots][14 floats]

    const int tid   = threadIdx.x;
    const int wid   = tid >> 6;        // 0 = scanner, 1 = loader
    const int lane  = tid & 63;
    const int b     = blockIdx.x;      // ONE batch row per block

    // ---------------- scanner per-lane config ----------------
    const int c     = lane >> 4;       // 0 = active chain
    const int slot  = lane & 15;
    const int chl   = slot >> 3;       // 0 = channel 1, 1 = channel 2
    const int role8 = slot & 7;        // 0:L 1:E 2:I 3:idle 4:L' 5:E' 6:T 7:M

    const float a0   = chl ? w24[12] : w24[0];
    const float W1v  = chl ? w24[13] : w24[1];
    const float W4v  = chl ? w24[16] : w24[4];
    const float W5x  = chl ? w24[17] : w24[5];
    const float W6v  = chl ? w24[18] : w24[6];
    const float W8v  = chl ? w24[20] : w24[8];
    const float W11v = chl ? w24[23] : w24[11];
    const float W2 = w24[2], W3 = w24[3], W9 = w24[9], W10 = w24[10];

    float pb, pcc, pd, v, u, wA, wB, wC, wD;
    float fL = 0.f, fE = 0.f, fITM = 0.f;
    int offs;
    if (role8 == 0 || role8 == 4) {        // L / L': w2*(zp*w1) + w3*z2(self)
        pb=0.20f; pcc=-65.f; pd=6.f;   v=-70.f; u=-14.f;
        wA=W2;  wB=W1v;  wC=0.f; wD=W3;  offs=0; fL=1.f;
    } else if (role8 == 1 || role8 == 5) { // E / E': zp*w4 + z2*w5 (z2 <- slot-1)
        pb=0.25f; pcc=-55.f; pd=0.05f; v=-64.f; u=-16.f;
        wA=1.f; wB=W4v;  wC=W5x; wD=0.f; offs=3; fE=1.f;
    } else if (role8 == 2) {               // I: z3*w6 (z3 <- slot-1 = E)
        pb=0.25f; pcc=-65.f; pd=6.f;   v=-64.f; u=-16.f;
        wA=1.f; wB=W6v;  wC=0.f; wD=0.f; offs=6; fITM=1.f;
    } else if (role8 == 6) {               // T: w9*(z3*w8)+w10*z5(self) (z3 <- slot-1 = E')
        pb=0.20f; pcc=-50.f; pd=2.f;   v=-70.f; u=-14.f;
        wA=W9;  wB=W8v;  wC=0.f; wD=W10; offs=6; fITM=1.f;
    } else if (role8 == 7) {               // M: z5*w11 (z5 <- slot-1 = T)
        pb=0.25f; pcc=-65.f; pd=6.f;   v=-64.f; u=-16.f;
        wA=1.f; wB=W11v; wC=0.f; wD=0.f; offs=9; fITM=1.f;
    } else {                               // slot 3: idle
        pb=0.25f; pcc=-65.f; pd=6.f;   v=-64.f; u=-16.f;
        wA=0.f; wB=0.f;  wC=0.f; wD=0.f; offs=9;
    }
    // ring pairs: p0=(z2,vL)@s0 p1=(z3,vE)@s1 p2=(z4,vI)@s2 p3=(z5,vT)@s6
    //             p4=(z6,vM)@s7 ; p5=(z62,vM2)@s15. Only chain 0 writes.
    const bool wr = (c == 0) &&
        ((chl == 0 && (role8 <= 2 || role8 == 6 || role8 == 7)) ||
         (chl == 1 && role8 == 7));
    int p = 0;
    if (role8 == 1) p = 1;
    else if (role8 == 2) p = 2;
    else if (role8 == 6) p = 3;
    else if (role8 == 7) p = chl ? 5 : 4;
    const int ringoff = 2 * p;

    float z_last = 0.f, in_p1 = 0.f, in_p2 = 0.f;
    float zp1 = 0.f, zp2 = 0.f, zp3 = 0.f;

    // loader mapping: atom t = lane>>2 (16 atoms), chunk = lane&3 (4x16 floats)
    const int latom = lane >> 2, lchunk = lane & 3;
    const float* inb = in + (size_t)b * T_ * 64;
    float4 A[4], Bv[4];                // ping-pong, static indexing

#define ISSUE(KK, BUF) {                                                       \
    const int t0i = 16 * (KK);                                                 \
    const int ttc = (t0i + latom <= 499) ? latom : 0;                          \
    const float* ap = inb + (size_t)(t0i + ttc) * 64 + lchunk * 16;            \
    _Pragma("unroll")                                                          \
    for (int ck = 0; ck < 4; ++ck) BUF[ck] = *(const float4*)(ap + ck * 4);    \
}

// Bit-exact tree: q_c=(x+y)+(z+w); lane holds chunks 4j..4j+3:
// a0=q0+q1, a1=q2+q3, bsum=a0+a1 (level-2 node); c=bsum+(lane^1);
// s=c+(lane^2). Commuted adds only -> bitwise identical to validated tree.
#define REDUCE(KK, BUF) {                                                      \
    float4 t_;                                                                 \
    t_ = BUF[0]; float q0_ = (t_.x + t_.y) + (t_.z + t_.w);                    \
    t_ = BUF[1]; float q1_ = (t_.x + t_.y) + (t_.z + t_.w);                    \
    t_ = BUF[2]; float q2_ = (t_.x + t_.y) + (t_.z + t_.w);                    \
    t_ = BUF[3]; float q3_ = (t_.x + t_.y) + (t_.z + t_.w);                    \
    float a0_ = q0_ + q1_, a1_ = q2_ + q3_;                                    \
    float bs_ = a0_ + a1_;                                                     \
    float cs_ = bs_ + dpp_qx1(bs_);                                            \
    float ss_ = cs_ + dpp_qx2(cs_);                                            \
    if (lchunk == 0)                                                           \
        S_lds[((KK) & 1) * 64 + latom] =                                       \
            (16 * (KK) + latom <= 499) ? ss_ : 0.f;                            \
}

#define SYS_ITER(SV, VEXPR, I_) {                                              \
    float in0 = in_p2;                                                         \
    in_p2 = in_p1;                                                             \
    in_p1 = dpp_shr1(z_last);                                                  \
    float zpc = (SV) * a0;                                                     \
    float X = (fL * zpc + fE * zp3) + fITM * in0;                              \
    float Isyn = wA * (X * wB) + wC * in0 + wD * z_last;                       \
    float znew = izh_m(v, u, Isyn, pb, pcc, pd, (VEXPR));                      \
    if (wr) *(float2*)(ringp + (I_) * 14) = make_float2(znew, v);              \
    zp3 = zp2; zp2 = zp1; zp1 = zpc;                                           \
    z_last = znew;                                                             \
}

#define GROUP16(VF)                                                            \
    SYS_ITER(g0.x, VF(0),  0)  SYS_ITER(g0.y, VF(1),  1)                       \
    SYS_ITER(g0.z, VF(2),  2)  SYS_ITER(g0.w, VF(3),  3)                       \
    SYS_ITER(g1.x, VF(4),  4)  SYS_ITER(g1.y, VF(5),  5)                       \
    SYS_ITER(g1.z, VF(6),  6)  SYS_ITER(g1.w, VF(7),  7)                       \
    SYS_ITER(g2.x, VF(8),  8)  SYS_ITER(g2.y, VF(9),  9)                       \
    SYS_ITER(g2.z, VF(10), 10) SYS_ITER(g2.w, VF(11), 11)                      \
    SYS_ITER(g3.x, VF(12), 12) SYS_ITER(g3.y, VF(13), 13)                      \
    SYS_ITER(g3.z, VF(14), 14) SYS_ITER(g3.w, VF(15), 15)

#define VF_PRO(i)  ((i) >= offs)
#define VF_ONE(i)  true
#define VF_EPI(i)  ((i) <= 3 + offs)

// DUMP(K): loader, one period behind. Lanes 0-15 only (one row). Ring reads
// stride 14 floats (56B) -> 16 distinct banks, conflict-free.
#define DUMP(K) {                                                              \
    const int td = lane & 15;                                                  \
    const int t  = 16 * (K) - 9 + td;                                          \
    if (lane < 16 && 0 <= t && t <= 499) {                                     \
        float2 a2 = *(const float2*)&ring[((t)     & 63) * 14 + 0];            \
        float2 b2 = *(const float2*)&ring[((t + 3) & 63) * 14 + 2];            \
        float2 c1 = *(const float2*)&ring[((t + 6) & 63) * 14 + 4];            \
        float2 c2 = *(const float2*)&ring[((t + 6) & 63) * 14 + 6];            \
        float2 e1 = *(const float2*)&ring[((t + 9) & 63) * 14 + 8];            \
        float2 e2 = *(const float2*)&ring[((t + 9) & 63) * 14 + 10];           \
        const size_t g = (size_t)b * T_ + t;                                   \
        out[g]          = e1.x;   /* o_spikes  = z6  */                        \
        out[BT + g]     = e1.y;   /* v         = vM  */                        \
        out[2 * BT + g] = e2.x;   /* o_spikes2 = z62 */                        \
        out[3 * BT + g] = e2.y;   /* v2        = vM2 */                        \
        ((float4*)out)[BT + g]     = make_float4(a2.x, b2.x, c1.x, c2.x);      \
        ((float4*)out)[2 * BT + g] = make_float4(a2.y, b2.y, c1.y, c2.y);      \
    }                                                                          \
}

// Scanner period K: ring slots (K&3)*16 .. +15.
#define SCANP(K, VFSEL) {                                                      \
    const float4* sp = (const float4*)(S_lds + ((K) & 1) * 64 + c * 16);       \
    float4 g0 = sp[0], g1 = sp[1], g2 = sp[2], g3 = sp[3];                     \
    float* ringp = ring + ((K) & 3) * 224 + ringoff;                           \
    GROUP16(VFSEL)                                                             \
}

    // ---------------- prologue ----------------
    if (wid == 1) {
        ISSUE(0, A)
        REDUCE(0, A)           // one-time vmcnt wait on first loads
        ISSUE(1, Bv)
    }
    BAR();                     // S_lds buf0 ready; ISSUE(1) stays in flight

    // ---------------- main: periods 0..31 (unrolled x2 for reg ping-pong) ---
    for (int k = 0; k < 32; k += 2) {
        if (wid == 0) {
            if (k == 0) { SCANP(k, VF_PRO) } else { SCANP(k, VF_ONE) }
        } else {
            if (k + 2 < 32) { ISSUE(k + 2, A) }
            if (k + 1 < 32) { REDUCE(k + 1, Bv) }
            if (k >= 1) { DUMP(k - 1) }
        }
        BAR();
        if (wid == 0) {
            if (k + 1 == 31) { SCANP(k + 1, VF_EPI) } else { SCANP(k + 1, VF_ONE) }
        } else {
            if (k + 3 < 32) { ISSUE(k + 3, Bv) }
            if (k + 2 < 32) { REDUCE(k + 2, A) }
            DUMP(k)
        }
        BAR();
    }
    // final dump (period 31's tail), after the last BAR
    if (wid == 1) { DUMP(31) }

#undef ISSUE
#undef REDUCE
#undef SYS_ITER
#undef GROUP16
#undef VF_PRO
#undef VF_ONE
#undef VF_EPI
#undef DUMP
#undef SCANP
}

extern "C" void kernel_launch(void* const* d_in, const int* in_sizes, int n_in,
                              void* d_out, int out_size, void* d_ws, size_t ws_size,
                              hipStream_t stream) {
    const float* in = (const float*)d_in[0];
    const float* w  = (const float*)d_in[1];
    float* out = (float*)d_out;

    // 2048 blocks x 128 threads (1 scanner + 1 loader wave), ONE row each.
    // 8 blocks/CU -> 2 scanner waves per SIMD -> dep-chain bubbles filled.
    fused_scan11_kernel<<<B_, 128, 0, stream>>>(in, w, out);
}